// Round 3
// baseline (900.089 us; speedup 1.0000x reference)
//
#include <hip/hip_runtime.h>

#define CURV 2.3026f
#define EPSF 1e-15f

typedef __attribute__((ext_vector_type(8))) short bfrag8;
typedef __attribute__((ext_vector_type(4))) float ffrag4;

__device__ __forceinline__ unsigned short f2bf(float f) {
  unsigned u = __builtin_bit_cast(unsigned, f);
  u += 0x7fffu + ((u >> 16) & 1u);
  return (unsigned short)(u >> 16);
}

// async global->LDS, 16B per lane; LDS dest = wave-uniform base + lane*16
__device__ __forceinline__ void gld16(const void* g, void* l) {
  unsigned lo = (unsigned)(unsigned long long)l;  // low 32 bits of generic LDS ptr = LDS offset
  __builtin_amdgcn_global_load_lds(
      (const __attribute__((address_space(1))) unsigned int*)g,
      (__attribute__((address_space(3))) unsigned int*)lo, 16, 0, 0);
}

// ---- weight prep: bf16 transpose + per-column stats {2(zn-1), cosh(tcr)/zn, sinh(tcr)} ----
__global__ void prep_weights(const float* __restrict__ z, const float* __restrict__ r,
                             unsigned short* __restrict__ zT, float* __restrict__ stats,
                             int K, int N) {
  int n = blockIdx.x, t = threadIdx.x;  // 128 threads
  float ss = 0.f;
  for (int k = t; k < K; k += 128) {
    float v = z[(size_t)k * N + n];
    ss += v * v;
    zT[(size_t)n * K + k] = f2bf(v);
  }
  __shared__ float red[128];
  red[t] = ss; __syncthreads();
  for (int s = 64; s > 0; s >>= 1) { if (t < s) red[t] += red[t + s]; __syncthreads(); }
  if (t == 0) {
    float zn = fmaxf(sqrtf(red[0]), EPSF);
    float cs = sqrtf(CURV);
    float tc = 2.f * cs * r[n];
    stats[4*n+0] = 2.f * (zn - 1.f);  // delta
    stats[4*n+1] = coshf(tc) / zn;
    stats[4*n+2] = sinhf(tc);
    stats[4*n+3] = 0.f;
  }
}

// ---- fused hlinear(+hrelu) layer: 128 x N tile, BK=64, 8 waves (2M x 4N), MFMA 16x16x32 bf16.
// LDS XOR-swizzle: 16B chunk c of row r stored at pos c^(r&7) (bf16 128B rows) / c^(r&15) (fp32 256B rows).
// A double-buffered (issued 1 K-step ahead), B single-buffered (staged between MID and TOP barriers).
template<int K, int N, bool FIRST, bool LAST>
__launch_bounds__(512, 2)
__global__ void hlayer(const void* __restrict__ Ain,          // FIRST: float BxK, else bf16 BxK
                       const unsigned short* __restrict__ zT, // N x K bf16
                       const float* __restrict__ stats,       // N x 4
                       const float* __restrict__ lamIn,       // B
                       unsigned short* __restrict__ Hout,     // B x N bf16 (unless LAST)
                       float* __restrict__ lamOut,            // B (unless LAST)
                       const float* __restrict__ z4,          // 128 (LAST only)
                       const float* __restrict__ st4,         // 4  (LAST only)
                       float* __restrict__ outF) {            // B  (LAST only)
  constexpr int NT = N / 64;
  constexpr int KI = K / 64;
  constexpr int AB = FIRST ? 128*256 : 128*128;
  constexpr int BB = N * 128;
  constexpr int STG = 2*AB + BB;
  constexpr int HSB = LAST ? 0 : 128*(N+8);
  constexpr int SM = STG > HSB ? STG : HSB;
  __shared__ __align__(16) char smem[SM];
  __shared__ float lamS[128];
  __shared__ float gamS[128];
  __shared__ float sums[3][128];

  const int t = threadIdx.x;
  const int wid = t >> 6, lane = t & 63;
  const int wm = wid >> 2, wn = wid & 3;
  const int lm = lane & 15, quad = lane >> 4;
  const int l7 = lane & 7;
  const unsigned rowg0 = blockIdx.x * 128;

  char* bufA0 = smem;
  char* bufA1 = smem + AB;
  char* Bs    = smem + 2*AB;

  // ---- staging offsets ----
  const char* Abase = (const char*)Ain;
  const char* Bbase = (const char*)zT;
  constexpr int NA = FIRST ? 4 : 2;
  constexpr int AADV = FIRST ? 256 : 128;
  unsigned aoff[NA], lAo[NA];
  if (FIRST) {
    int rl4 = lane >> 4, c0 = (lane & 15) ^ rl4;
#pragma unroll
    for (int j = 0; j < 4; j++) {
      aoff[j] = (rowg0 + 16*wid + 4*j + rl4) * (unsigned)(K*4) + ((unsigned)(c0 ^ (4*j)) << 4);
      lAo[j]  = (16*wid + 4*j) * 256;
    }
  } else {
    int rl8 = lane >> 3, c0 = l7 ^ rl8;
#pragma unroll
    for (int j = 0; j < NA; j++) {
      aoff[j] = (rowg0 + 16*wid + 8*j + rl8) * (unsigned)(K*2) + ((unsigned)c0 << 4);
      lAo[j]  = (16*wid + 8*j) * 128;
    }
  }
  unsigned boff[NT], lBo[NT];
  {
    int rl8 = lane >> 3, c0 = l7 ^ rl8;
#pragma unroll
    for (int j = 0; j < NT; j++) {
      boff[j] = (8*(NT*wid + j) + rl8) * (unsigned)(K*2) + ((unsigned)c0 << 4);
      lBo[j]  = (8*(NT*wid + j)) * 128;
    }
  }

  // prologue: A(0) -> bufA0, B(0) -> Bs
#pragma unroll
  for (int j = 0; j < NA; j++) { gld16(Abase + aoff[j], bufA0 + lAo[j]); aoff[j] += AADV; }
#pragma unroll
  for (int j = 0; j < NT; j++) { gld16(Bbase + boff[j], Bs + lBo[j]); boff[j] += 128; }

  ffrag4 acc[4][NT];
#pragma unroll
  for (int a = 0; a < 4; a++)
#pragma unroll
    for (int b = 0; b < NT; b++) acc[a][b] = (ffrag4){0.f, 0.f, 0.f, 0.f};

  float ssA[4] = {0.f, 0.f, 0.f, 0.f};

  const unsigned afbase = FIRST ? (64*wm + lm)*256 : (64*wm + lm)*128;
  const unsigned bfbase = (wn*(N/4) + lm)*128;

#pragma unroll 2
  for (int k = 0; k < KI; k++) {
    __syncthreads();  // TOP: A(k), B(k) drained; prev readers of next-A buf done
    char* curA = (k & 1) ? bufA1 : bufA0;
    char* nxtA = (k & 1) ? bufA0 : bufA1;
    if (k + 1 < KI) {
#pragma unroll
      for (int j = 0; j < NA; j++) { gld16(Abase + aoff[j], nxtA + lAo[j]); aoff[j] += AADV; }
    }
#pragma unroll
    for (int s = 0; s < 2; s++) {
      bfrag8 af[4];
      if (FIRST) {
#pragma unroll
        for (int tm = 0; tm < 4; tm++) {
          const char* p = curA + afbase + tm*4096;
          float4 f0 = *(const float4*)(p + (((8*s + 2*quad + 0) ^ lm) << 4));
          float4 f1 = *(const float4*)(p + (((8*s + 2*quad + 1) ^ lm) << 4));
          ssA[tm] += f0.x*f0.x + f0.y*f0.y + f0.z*f0.z + f0.w*f0.w
                   + f1.x*f1.x + f1.y*f1.y + f1.z*f1.z + f1.w*f1.w;
          bfrag8 a;
          a[0]=(short)f2bf(f0.x); a[1]=(short)f2bf(f0.y); a[2]=(short)f2bf(f0.z); a[3]=(short)f2bf(f0.w);
          a[4]=(short)f2bf(f1.x); a[5]=(short)f2bf(f1.y); a[6]=(short)f2bf(f1.z); a[7]=(short)f2bf(f1.w);
          af[tm] = a;
        }
      } else {
#pragma unroll
        for (int tm = 0; tm < 4; tm++)
          af[tm] = *(const bfrag8*)(curA + afbase + tm*2048 + (((4*s + quad) ^ l7) << 4));
      }
#pragma unroll
      for (int tn = 0; tn < NT; tn++) {
        bfrag8 bf = *(const bfrag8*)(Bs + bfbase + tn*2048 + (((4*s + quad) ^ l7) << 4));
#pragma unroll
        for (int tm = 0; tm < 4; tm++)
          acc[tm][tn] = __builtin_amdgcn_mfma_f32_16x16x32_bf16(af[tm], bf, acc[tm][tn], 0, 0, 0);
      }
    }
    __syncthreads();  // MID: all waves done reading Bs
    if (k + 1 < KI) {
#pragma unroll
      for (int j = 0; j < NT; j++) { gld16(Bbase + boff[j], Bs + lBo[j]); boff[j] += 128; }
    }
  }

  // ---- epilogue ----
  if (FIRST) {
#pragma unroll
    for (int tm = 0; tm < 4; tm++) {
      float v = ssA[tm];
      v += __shfl_xor(v, 16);
      v += __shfl_xor(v, 32);
      if (wn == 0 && quad == 0)
        lamS[64*wm + 16*tm + lm] = 2.f / (1.f - CURV * v);
    }
  }
  if (t < 128) {
    sums[0][t] = 0.f; sums[1][t] = 0.f; sums[2][t] = 0.f;
    if (!FIRST) lamS[t] = lamIn[rowg0 + t];
  }
  float z4v[NT];
  if (LAST) {
#pragma unroll
    for (int tn = 0; tn < NT; tn++) z4v[tn] = z4[wn*(N/4) + 16*tn + lm];
  }
  __syncthreads();

  const float cs = sqrtf(CURV), inv_cs = 1.f / cs;

  // s -> w via polynomial sinh(2*zn*asinh(g)) expansion (|g|<=~0.35, |delta|<=~0.16)
#pragma unroll
  for (int tn = 0; tn < NT; tn++) {
    float4 st = *(const float4*)(stats + 4*(wn*(N/4) + 16*tn + lm));
    float dl = st.x, chozn = st.y, sh = st.z;
#pragma unroll
    for (int tm = 0; tm < 4; tm++) {
#pragma unroll
      for (int rg = 0; rg < 4; rg++) {
        float lam = lamS[64*wm + 16*tm + 4*quad + rg];
        float g = cs * lam * acc[tm][tn][rg] * chozn - (lam - 1.f) * sh;
        float q = g * g;
        float u = g * (1.f - q*(1.f/6.f) + q*q*0.075f - q*q*q*0.044642857f);
        float d1 = dl * u;
        float S = 2.f * g * sqrtf(1.f + q);
        float Ch = 1.f + 2.f*q;
        acc[tm][tn][rg] = (S * (1.f + 0.5f*d1*d1) + Ch * d1) * inv_cs;
      }
    }
  }
  // row reductions: sum w^2, sum relu(w)^2, (LAST) sum relu(w)*z4
#pragma unroll
  for (int tm = 0; tm < 4; tm++) {
#pragma unroll
    for (int rg = 0; rg < 4; rg++) {
      float s2 = 0.f, sp2 = 0.f, s4 = 0.f;
#pragma unroll
      for (int tn = 0; tn < NT; tn++) {
        float w = acc[tm][tn][rg];
        s2 += w * w;
        float wp = fmaxf(w, 0.f);
        sp2 += wp * wp;
        if (LAST) s4 += wp * z4v[tn];
      }
#pragma unroll
      for (int m = 1; m <= 8; m <<= 1) {
        s2 += __shfl_xor(s2, m, 16);
        sp2 += __shfl_xor(sp2, m, 16);
        if (LAST) s4 += __shfl_xor(s4, m, 16);
      }
      if (lm == 0) {
        int row = 64*wm + 16*tm + 4*quad + rg;
        atomicAdd(&sums[0][row], s2);
        atomicAdd(&sums[1][row], sp2);
        if (LAST) atomicAdd(&sums[2][row], s4);
      }
    }
  }
  __syncthreads();
  if (t < 128) {
    float sw2 = sums[0][t], swp2 = sums[1][t];
    float den = 1.f + sqrtf(1.f + CURV * sw2);
    float nn = fmaxf(sqrtf(sw2) / den, EPSF);
    float al = atanhf(fminf(cs * nn, 1.f - 1e-7f)) / (cs * nn);
    float vn = fmaxf(al * sqrtf(swp2) / den, EPSF);
    float be = tanhf(cs * vn) / (cs * vn);
    float gam = al * be / den;
    if (LAST) {
      float s = gam * sums[2][t];
      float lamh = 2.f / (1.f - CURV * gam * gam * swp2);
      float g = cs * lamh * s * st4[1] - (lamh - 1.f) * st4[2];
      float q = g * g;
      float u = g * (1.f - q*(1.f/6.f) + q*q*0.075f - q*q*q*0.044642857f);
      float d1 = st4[0] * u;
      float S = 2.f * g * sqrtf(1.f + q);
      float Ch = 1.f + 2.f*q;
      float w = (S * (1.f + 0.5f*d1*d1) + Ch * d1) * inv_cs;
      outF[rowg0 + t] = w / (1.f + sqrtf(1.f + CURV * w * w));
    } else {
      gamS[t] = gam;
      lamOut[rowg0 + t] = 2.f / (1.f - CURV * gam * gam * swp2);
    }
  }
  if (!LAST) {
    __syncthreads();
    unsigned short* HS = (unsigned short*)smem;  // staging dead; repack 64 rows at a time
#pragma unroll
    for (int h = 0; h < 2; h++) {
      if (wm == h) {
#pragma unroll
        for (int tm = 0; tm < 4; tm++)
#pragma unroll
          for (int rg = 0; rg < 4; rg++) {
            int rloc = 16*tm + 4*quad + rg;
            float gam = gamS[64*h + rloc];
#pragma unroll
            for (int tn = 0; tn < NT; tn++)
              HS[rloc*(N+8) + wn*(N/4) + 16*tn + lm] = f2bf(gam * fmaxf(acc[tm][tn][rg], 0.f));
          }
      }
      __syncthreads();
      constexpr int NS8 = N / 8;
      constexpr int SL = (8 * N) / 512;
#pragma unroll
      for (int u = 0; u < SL; u++) {
        int sl = t + 512*u;
        int rl = sl / NS8, cc = sl % NS8;
        uint4 v = *(const uint4*)(HS + rl*(N+8) + cc*8);
        *(uint4*)((unsigned short*)Hout + (size_t)(rowg0 + 64*h + rl)*N + cc*8) = v;
      }
      __syncthreads();
    }
  }
}

extern "C" void kernel_launch(void* const* d_in, const int* in_sizes, int n_in,
                              void* d_out, int out_size, void* d_ws, size_t ws_size,
                              hipStream_t stream) {
  const float* x  = (const float*)d_in[0];
  const float* z1 = (const float*)d_in[1];
  const float* b1 = (const float*)d_in[2];
  const float* z2 = (const float*)d_in[3];
  const float* b2 = (const float*)d_in[4];
  const float* z3 = (const float*)d_in[5];
  const float* b3 = (const float*)d_in[6];
  const float* z4 = (const float*)d_in[7];
  const float* b4 = (const float*)d_in[8];

  char* ws = (char*)d_ws; size_t off = 0;
  auto carve = [&](size_t b) { char* p = ws + off; off += (b + 255) & ~(size_t)255; return p; };
  unsigned short* zT1 = (unsigned short*)carve(512*768*2);
  unsigned short* zT2 = (unsigned short*)carve(256*512*2);
  unsigned short* zT3 = (unsigned short*)carve(128*256*2);
  unsigned short* zT4 = (unsigned short*)carve(128*2);
  float* st1 = (float*)carve(512*4*4);
  float* st2 = (float*)carve(256*4*4);
  float* st3 = (float*)carve(128*4*4);
  float* st4 = (float*)carve(4*4);
  float* lam1 = (float*)carve(65536*4);
  float* lam2 = (float*)carve(65536*4);
  unsigned short* h1 = (unsigned short*)carve((size_t)65536*512*2);
  unsigned short* h2 = (unsigned short*)carve((size_t)65536*256*2);

  prep_weights<<<512, 128, 0, stream>>>(z1, b1, zT1, st1, 768, 512);
  prep_weights<<<256, 128, 0, stream>>>(z2, b2, zT2, st2, 512, 256);
  prep_weights<<<128, 128, 0, stream>>>(z3, b3, zT3, st3, 256, 128);
  prep_weights<<<1,   128, 0, stream>>>(z4, b4, zT4, st4, 128, 1);

  hlayer<768, 512, true,  false><<<512, 512, 0, stream>>>(x,  zT1, st1, nullptr, h1, lam1, nullptr, nullptr, nullptr);
  hlayer<512, 256, false, false><<<512, 512, 0, stream>>>(h1, zT2, st2, lam1,    h2, lam2, nullptr, nullptr, nullptr);
  hlayer<256, 128, false, true ><<<512, 512, 0, stream>>>(h2, zT3, st3, lam2,    nullptr, nullptr, z4, st4, (float*)d_out);
}

// Round 4
// 510.304 us; speedup vs baseline: 1.7638x; 1.7638x over previous
//
#include <hip/hip_runtime.h>

#define CURV 2.3026f
#define EPSF 1e-15f

typedef __attribute__((ext_vector_type(8))) short bfrag8;
typedef __attribute__((ext_vector_type(4))) float ffrag4;

__device__ __forceinline__ unsigned short f2bf(float f) {
  unsigned u = __builtin_bit_cast(unsigned, f);
  u += 0x7fffu + ((u >> 16) & 1u);
  return (unsigned short)(u >> 16);
}

// async global->LDS, 16B per lane; LDS dest = wave-uniform base + lane*16 (global side is per-lane)
__device__ __forceinline__ void gld16(const void* g, void* l) {
  unsigned lo = (unsigned)(unsigned long long)l;
  __builtin_amdgcn_global_load_lds(
      (const __attribute__((address_space(1))) unsigned int*)g,
      (__attribute__((address_space(3))) unsigned int*)lo, 16, 0, 0);
}

// ---- x prepass: fp32 -> bf16 + lambda0 = 2/(1 - c*||x||^2) ----
__global__ __launch_bounds__(256) void xprep(const float* __restrict__ x,
                                             unsigned short* __restrict__ xb,
                                             float* __restrict__ lam0) {
  const int t = threadIdx.x, lane = t & 63, w = t >> 6;
  const long row = (long)blockIdx.x * 4 + w;
  const float* xr = x + row * 768;
  unsigned short* xo = xb + row * 768;
  float ss = 0.f;
#pragma unroll
  for (int j = 0; j < 3; j++) {
    float4 v = *(const float4*)(xr + 4 * (lane + 64 * j));
    ss += v.x * v.x + v.y * v.y + v.z * v.z + v.w * v.w;
    ushort4 b; b.x = f2bf(v.x); b.y = f2bf(v.y); b.z = f2bf(v.z); b.w = f2bf(v.w);
    *(ushort4*)(xo + 4 * (lane + 64 * j)) = b;
  }
#pragma unroll
  for (int m = 1; m <= 32; m <<= 1) ss += __shfl_xor(ss, m);
  if (lane == 0) lam0[row] = 2.f / (1.f - CURV * ss);
}

// ---- weight prep: bf16 transpose + per-column stats {2(zn-1), cosh(tcr)/zn, sinh(tcr), 0} ----
__global__ void prep_weights(const float* __restrict__ z, const float* __restrict__ r,
                             unsigned short* __restrict__ zT, float* __restrict__ stats,
                             int K, int N) {
  int n = blockIdx.x, t = threadIdx.x;  // 128 threads
  float ss = 0.f;
  for (int k = t; k < K; k += 128) {
    float v = z[(size_t)k * N + n];
    ss += v * v;
    zT[(size_t)n * K + k] = f2bf(v);
  }
  __shared__ float red[128];
  red[t] = ss; __syncthreads();
  for (int s = 64; s > 0; s >>= 1) { if (t < s) red[t] += red[t + s]; __syncthreads(); }
  if (t == 0) {
    float zn = fmaxf(sqrtf(red[0]), EPSF);
    float cs = sqrtf(CURV);
    float tc = 2.f * cs * r[n];
    stats[4*n+0] = 2.f * (zn - 1.f);
    stats[4*n+1] = coshf(tc) / zn;
    stats[4*n+2] = sinhf(tc);
    stats[4*n+3] = 0.f;
  }
}

// ---- fused hlinear(+hrelu): 64 x N tile, BK=32, 8 waves (2M x 4N), acc[2][NT] (<=64 VGPR).
// A,B both double-buffered via gld16; ONE barrier per K-step: barrier -> issue(k+1) -> compute(k).
// LDS layout: paired rows — LDS row R (128B) holds data-row 2R (chunks 0-3) and 2R+1 (chunks 4-7),
// 16B chunk c stored at slot c^(R&7). Frag reads are b128 with <=2-way bank aliasing (free).
template<int K, int N, bool LAST>
__launch_bounds__(512, 2)
__global__ void hlayer(const unsigned short* __restrict__ Ain,  // B x K bf16
                       const unsigned short* __restrict__ zT,   // N x K bf16
                       const float* __restrict__ stats,         // N x 4
                       const float* __restrict__ lamIn,         // B
                       unsigned short* __restrict__ Hout,       // B x N bf16 (unless LAST)
                       float* __restrict__ lamOut,              // B (unless LAST)
                       const float* __restrict__ z4,            // 128 (LAST only)
                       const float* __restrict__ st4,           // 4  (LAST only)
                       float* __restrict__ outF) {              // B  (LAST only)
  constexpr int NT = N / 64;          // 16-col tiles per wave
  constexpr int KI = K / 32;          // K-steps
  constexpr int NBW = N / 128;        // B gld16 issues per wave per step
  constexpr int BUF = 4096 + N * 64;  // A(64x32 bf16 = 4KB) + B(N x 32 bf16)
  constexpr int HSB = LAST ? 0 : 64 * (N + 8) * 2;
  constexpr int SM = (2 * BUF > HSB) ? 2 * BUF : HSB;
  __shared__ __align__(16) char smem[SM];
  __shared__ float lamS[64];
  __shared__ float gamS[64];
  __shared__ float sums[3][64];

  const int t = threadIdx.x;
  const int wid = t >> 6, lane = t & 63;
  const int wm = wid >> 2, wn = wid & 3;
  const int lm = lane & 15, quad = lane >> 4;
  const int l7 = lane & 7, rl8 = lane >> 3;
  const unsigned rowg0 = blockIdx.x * 64;

  // ---- staging addresses (static per lane; advance 64B per K-step) ----
  // A: 32 LDS rows, 4 issues on waves 0-3. B: N/2 LDS rows, NBW issues per wave.
  const char* Abase = (const char*)Ain;
  const char* Bbase = (const char*)zT;
  unsigned aoff = 0, aLds = 0;
  if (wid < 4) {
    unsigned R = 8 * wid + rl8;
    unsigned c = l7 ^ rl8;                       // R&7 == rl8
    unsigned m = 2 * R + (c >> 2);
    aoff = (rowg0 + m) * (unsigned)(K * 2) + (c & 3) * 16;
    aLds = wid * 1024 + lane * 16;
  }
  unsigned boff[NBW], bLds[NBW];
#pragma unroll
  for (int j = 0; j < NBW; j++) {
    unsigned R = 8 * (wid + 8 * j) + rl8;
    unsigned c = l7 ^ rl8;
    unsigned n = 2 * R + (c >> 2);
    boff[j] = n * (unsigned)(K * 2) + (c & 3) * 16;
    bLds[j] = (wid + 8 * j) * 1024 + lane * 16;
  }

  // frag-read offsets (slot = ((lm&1)*4 + quad) ^ (lm>>1), same for A and B)
  const unsigned sl16 = ((((lm & 1) << 2) + quad) ^ (lm >> 1)) << 4;
  unsigned afoff[2], bfoff[NT];
#pragma unroll
  for (int tm = 0; tm < 2; tm++)
    afoff[tm] = (16 * wm + 8 * tm + (lm >> 1)) * 128 + sl16;
#pragma unroll
  for (int tn = 0; tn < NT; tn++)
    bfoff[tn] = 4096 + (wn * (N / 8) + 8 * tn + (lm >> 1)) * 128 + sl16;

  // prologue: issue step 0 into buf0
  {
    char* buf = smem;
    if (wid < 4) gld16(Abase + aoff, buf + aLds);
#pragma unroll
    for (int j = 0; j < NBW; j++) gld16(Bbase + boff[j], buf + 4096 + bLds[j]);
  }

  ffrag4 acc[2][NT];
#pragma unroll
  for (int a = 0; a < 2; a++)
#pragma unroll
    for (int b = 0; b < NT; b++) acc[a][b] = (ffrag4){0.f, 0.f, 0.f, 0.f};

  for (int k = 0; k < KI; k++) {
    __syncthreads();  // drains issue(k) (launched one step ago); prior readers of next buf done
    char* cur = smem + (k & 1) * BUF;
    char* nxt = smem + ((k + 1) & 1) * BUF;
    if (k + 1 < KI) {
      unsigned adv = (unsigned)(k + 1) * 64;
      if (wid < 4) gld16(Abase + aoff + adv, nxt + aLds);
#pragma unroll
      for (int j = 0; j < NBW; j++) gld16(Bbase + boff[j] + adv, nxt + 4096 + bLds[j]);
    }
    bfrag8 af0 = *(const bfrag8*)(cur + afoff[0]);
    bfrag8 af1 = *(const bfrag8*)(cur + afoff[1]);
#pragma unroll
    for (int tn = 0; tn < NT; tn++) {
      bfrag8 bf = *(const bfrag8*)(cur + bfoff[tn]);
      acc[0][tn] = __builtin_amdgcn_mfma_f32_16x16x32_bf16(af0, bf, acc[0][tn], 0, 0, 0);
      acc[1][tn] = __builtin_amdgcn_mfma_f32_16x16x32_bf16(af1, bf, acc[1][tn], 0, 0, 0);
    }
  }

  // ---- epilogue ----
  if (t < 64) {
    sums[0][t] = 0.f; sums[1][t] = 0.f; sums[2][t] = 0.f;
    lamS[t] = lamIn[rowg0 + t];
  }
  float z4v[NT];
  if (LAST) {
#pragma unroll
    for (int tn = 0; tn < NT; tn++) z4v[tn] = z4[wn * (N / 4) + 16 * tn + lm];
  }
  __syncthreads();

  const float cs = sqrtf(CURV), inv_cs = 1.f / cs;

  // s -> w via polynomial sinh(2*zn*asinh(g)) expansion (|g|<~0.35, |delta|<~0.16)
#pragma unroll
  for (int tn = 0; tn < NT; tn++) {
    float4 st = *(const float4*)(stats + 4 * (wn * (N / 4) + 16 * tn + lm));
    float dl = st.x, chozn = st.y, sh = st.z;
#pragma unroll
    for (int tm = 0; tm < 2; tm++) {
#pragma unroll
      for (int rg = 0; rg < 4; rg++) {
        float lam = lamS[32 * wm + 16 * tm + 4 * quad + rg];
        float g = cs * lam * acc[tm][tn][rg] * chozn - (lam - 1.f) * sh;
        float q = g * g;
        float u = g * (1.f - q * (1.f / 6.f) + q * q * 0.075f - q * q * q * 0.044642857f);
        float d1 = dl * u;
        float S = 2.f * g * sqrtf(1.f + q);
        float Ch = 1.f + 2.f * q;
        acc[tm][tn][rg] = (S * (1.f + 0.5f * d1 * d1) + Ch * d1) * inv_cs;
      }
    }
  }
  // row reductions: sum w^2, sum relu(w)^2, (LAST) sum relu(w)*z4
#pragma unroll
  for (int tm = 0; tm < 2; tm++) {
#pragma unroll
    for (int rg = 0; rg < 4; rg++) {
      float s2 = 0.f, sp2 = 0.f, s4 = 0.f;
#pragma unroll
      for (int tn = 0; tn < NT; tn++) {
        float w = acc[tm][tn][rg];
        s2 += w * w;
        float wp = fmaxf(w, 0.f);
        sp2 += wp * wp;
        if (LAST) s4 += wp * z4v[tn];
      }
#pragma unroll
      for (int m = 1; m <= 8; m <<= 1) {
        s2 += __shfl_xor(s2, m, 16);
        sp2 += __shfl_xor(sp2, m, 16);
        if (LAST) s4 += __shfl_xor(s4, m, 16);
      }
      if (lm == 0) {
        int row = 32 * wm + 16 * tm + 4 * quad + rg;
        atomicAdd(&sums[0][row], s2);
        atomicAdd(&sums[1][row], sp2);
        if (LAST) atomicAdd(&sums[2][row], s4);
      }
    }
  }
  __syncthreads();
  if (t < 64) {
    float sw2 = sums[0][t], swp2 = sums[1][t];
    float den = 1.f + sqrtf(1.f + CURV * sw2);
    float nn = fmaxf(sqrtf(sw2) / den, EPSF);
    float al = atanhf(fminf(cs * nn, 1.f - 1e-7f)) / (cs * nn);
    float vn = fmaxf(al * sqrtf(swp2) / den, EPSF);
    float be = tanhf(cs * vn) / (cs * vn);
    float gam = al * be / den;
    if (LAST) {
      float s = gam * sums[2][t];
      float lamh = 2.f / (1.f - CURV * gam * gam * swp2);
      float g = cs * lamh * s * st4[1] - (lamh - 1.f) * st4[2];
      float q = g * g;
      float u = g * (1.f - q * (1.f / 6.f) + q * q * 0.075f - q * q * q * 0.044642857f);
      float d1 = st4[0] * u;
      float S = 2.f * g * sqrtf(1.f + q);
      float Ch = 1.f + 2.f * q;
      float w = (S * (1.f + 0.5f * d1 * d1) + Ch * d1) * inv_cs;
      outF[rowg0 + t] = w / (1.f + sqrtf(1.f + CURV * w * w));
    } else {
      gamS[t] = gam;
      lamOut[rowg0 + t] = 2.f / (1.f - CURV * gam * gam * swp2);
    }
  }
  if (!LAST) {
    __syncthreads();
    unsigned short* HS = (unsigned short*)smem;  // staging dead; repack 64 rows
#pragma unroll
    for (int tm = 0; tm < 2; tm++)
#pragma unroll
      for (int rg = 0; rg < 4; rg++) {
        int rloc = 32 * wm + 16 * tm + 4 * quad + rg;
        float gam = gamS[rloc];
#pragma unroll
        for (int tn = 0; tn < NT; tn++)
          HS[rloc * (N + 8) + wn * (N / 4) + 16 * tn + lm] = f2bf(gam * fmaxf(acc[tm][tn][rg], 0.f));
      }
    __syncthreads();
    constexpr int NS8 = N / 8;
    constexpr int SL = (8 * N) / 512;  // uint4 copies per thread
#pragma unroll
    for (int u = 0; u < SL; u++) {
      int sl = t + 512 * u;
      int rl = sl / NS8, cc = sl % NS8;
      uint4 v = *(const uint4*)(HS + rl * (N + 8) + cc * 8);
      *(uint4*)((unsigned short*)Hout + (size_t)(rowg0 + rl) * N + cc * 8) = v;
    }
  }
}

extern "C" void kernel_launch(void* const* d_in, const int* in_sizes, int n_in,
                              void* d_out, int out_size, void* d_ws, size_t ws_size,
                              hipStream_t stream) {
  const float* x  = (const float*)d_in[0];
  const float* z1 = (const float*)d_in[1];
  const float* b1 = (const float*)d_in[2];
  const float* z2 = (const float*)d_in[3];
  const float* b2 = (const float*)d_in[4];
  const float* z3 = (const float*)d_in[5];
  const float* b3 = (const float*)d_in[6];
  const float* z4 = (const float*)d_in[7];
  const float* b4 = (const float*)d_in[8];

  char* ws = (char*)d_ws; size_t off = 0;
  auto carve = [&](size_t b) { char* p = ws + off; off += (b + 255) & ~(size_t)255; return p; };
  unsigned short* zT1 = (unsigned short*)carve(512 * 768 * 2);
  unsigned short* zT2 = (unsigned short*)carve(256 * 512 * 2);
  unsigned short* zT3 = (unsigned short*)carve(128 * 256 * 2);
  unsigned short* zT4 = (unsigned short*)carve(128 * 2);
  float* st1 = (float*)carve(512 * 4 * 4);
  float* st2 = (float*)carve(256 * 4 * 4);
  float* st3 = (float*)carve(128 * 4 * 4);
  float* st4 = (float*)carve(4 * 4);
  float* lam0 = (float*)carve(65536 * 4);
  float* lam1 = (float*)carve(65536 * 4);
  float* lam2 = (float*)carve(65536 * 4);
  unsigned short* xb = (unsigned short*)carve((size_t)65536 * 768 * 2);
  unsigned short* h1 = (unsigned short*)carve((size_t)65536 * 512 * 2);
  unsigned short* h2 = (unsigned short*)carve((size_t)65536 * 256 * 2);

  xprep<<<16384, 256, 0, stream>>>(x, xb, lam0);
  prep_weights<<<512, 128, 0, stream>>>(z1, b1, zT1, st1, 768, 512);
  prep_weights<<<256, 128, 0, stream>>>(z2, b2, zT2, st2, 512, 256);
  prep_weights<<<128, 128, 0, stream>>>(z3, b3, zT3, st3, 256, 128);
  prep_weights<<<1,   128, 0, stream>>>(z4, b4, zT4, st4, 128, 1);

  hlayer<768, 512, false><<<1024, 512, 0, stream>>>(xb, zT1, st1, lam0, h1, lam1, nullptr, nullptr, nullptr);
  hlayer<512, 256, false><<<1024, 512, 0, stream>>>(h1, zT2, st2, lam1, h2, lam2, nullptr, nullptr, nullptr);
  hlayer<256, 128, true ><<<1024, 512, 0, stream>>>(h2, zT3, st3, lam2, nullptr, nullptr, z4, st4, (float*)d_out);
}